// Round 14
// baseline (83.377 us; speedup 1.0000x reference)
//
#include <hip/hip_runtime.h>

// B=8, L=512, D=512, H=8. Q/K GEMMs: M=4096, N=4096, K=512 -- fp8-e4m3 MFMA.
// R14: gemm unchanged (R13 4-phase, invariant across schedules). Tail kernels tuned:
// mfscores dual-acc ILP; ykern lc=8 (2 blocks/CU); finalize parallel pb-scan.
// V path (all f32): P' = softmax + 63.875; Y = sum_l P'*Xv; out = Y @ Wv + c*bv.

using f32x4 = __attribute__((ext_vector_type(4))) float;

#define GLOAD16(gp, lp) __builtin_amdgcn_global_load_lds( \
    (const __attribute__((address_space(1))) unsigned int*)(gp), \
    (__attribute__((address_space(3))) unsigned int*)(lp), 16, 0, 0)

// ---------------- kernel 1: prep = convert Xq/Xk -> fp8 (z=0,1); transpose W*16 -> fp8 (z=2,3)
__global__ __launch_bounds__(256) void prep(
    const float* __restrict__ x0, const float* __restrict__ x1,
    unsigned char* __restrict__ o0, unsigned char* __restrict__ o1,
    const float* __restrict__ w0, const float* __restrict__ w1,
    unsigned char* __restrict__ t0, unsigned char* __restrict__ t1)
{
    const int z = blockIdx.z;
    if (z < 2) {
        const float* src = (z == 0) ? x0 : x1;
        unsigned char* dst = (z == 0) ? o0 : o1;
        int i = (blockIdx.x * 256 + threadIdx.x) * 8;
        if (i < 2097152) {
            float4 a = *(const float4*)(src + i);
            float4 b = *(const float4*)(src + i + 4);
            uint2 u;
            u.x = __builtin_amdgcn_cvt_pk_fp8_f32(a.x, a.y, 0u, false);
            u.x = __builtin_amdgcn_cvt_pk_fp8_f32(a.z, a.w, u.x, true);
            u.y = __builtin_amdgcn_cvt_pk_fp8_f32(b.x, b.y, 0u, false);
            u.y = __builtin_amdgcn_cvt_pk_fp8_f32(b.z, b.w, u.y, true);
            *(uint2*)(dst + i) = u;
        }
    } else {
        const float* W = (z == 2) ? w0 : w1;
        unsigned char* T = (z == 2) ? t0 : t1;
        __shared__ float tile[32][33];
        const int n0 = (blockIdx.x & 127) * 32, k0 = (blockIdx.x >> 7) * 32;
        const int tx = threadIdx.x & 31, ty = threadIdx.x >> 5;   // (32, 8)
        #pragma unroll
        for (int j = 0; j < 32; j += 8)
            tile[ty + j][tx] = W[(size_t)(k0 + ty + j) * 4096 + n0 + tx];
        __syncthreads();
        const int n = ty * 4 + (tx >> 3), kq = tx & 7;
        unsigned int pk = __builtin_amdgcn_cvt_pk_fp8_f32(
            16.f * tile[kq * 4 + 0][n], 16.f * tile[kq * 4 + 1][n], 0u, false);
        pk = __builtin_amdgcn_cvt_pk_fp8_f32(
            16.f * tile[kq * 4 + 2][n], 16.f * tile[kq * 4 + 3][n], pk, true);
        *(unsigned int*)(T + (size_t)(n0 + n) * 512 + k0 + kq * 4) = pk;
    }
}

// ---------------- kernel 2: 256^2 FP8 GEMM, 64KB row-pair-packed LDS, 4-phase --------
__global__ __launch_bounds__(512) void gemm_bt256(
    const unsigned char* __restrict__ a0, const unsigned char* __restrict__ a1,
    const unsigned char* __restrict__ w0, const unsigned char* __restrict__ w1,
    const float* __restrict__ b0, const float* __restrict__ b1,
    unsigned char* __restrict__ c0, unsigned char* __restrict__ c1)
{
    const unsigned char* A;  const unsigned char* Bt; const float* bias; unsigned char* C;
    if (blockIdx.z == 0) { A = a0; Bt = w0; bias = b0; C = c0; }
    else                 { A = a1; Bt = w1; bias = b1; C = c1; }

    __shared__ __align__(16) unsigned char SH[65536];

    const int tid  = threadIdx.x;
    const int lane = tid & 63;
    const int wid  = tid >> 6;
    const int wr   = wid >> 2;
    const int wn   = wid & 3;
    const int linb = blockIdx.y * 16 + blockIdx.x;
    const int swz  = (linb & 7) * 32 + (linb >> 3);
    const int bx   = (swz >> 6) * 4 + (swz & 3);
    const int by   = (swz >> 2) & 15;
    const int row0 = by * 256;
    const int n0   = bx * 256;

    const int lgs = (tid & 7) ^ ((tid >> 3) & 7);
    const int shi = lgs >> 2, slo = lgs & 3;
    const int srow0 = (tid >> 3) + shi * 128;
    const unsigned char* gA = A  + (size_t)(row0 + srow0) * 512 + slo * 16;
    const unsigned char* gB = Bt + (size_t)(n0   + srow0) * 512 + slo * 16;

#define STAGE_A(gp, buf, c, trel)                                                 \
    GLOAD16((gp) + (c) * (64 * 512) + (trel) * 64,                                \
            SH + (buf) * 16384 + (c) * 8192 + wid * 1024)
#define STAGE_B(gp, buf, c, trel)                                                 \
    GLOAD16((gp) + (c) * (64 * 512) + (trel) * 64,                                \
            SH + 32768 + (buf) * 16384 + (c) * 8192 + wid * 1024)

    const int l7 = lane & 7, koh = lane >> 5, kol = (lane >> 4) & 1, l15 = lane & 15;
    const char* bA0 = (const char*)SH + l15 * 128 + (((0 * 2 + koh + wr * 4) ^ l7) << 4) + kol * 8;
    const char* bA1 = (const char*)SH + l15 * 128 + (((1 * 2 + koh + wr * 4) ^ l7) << 4) + kol * 8;
    const char* bB0 = (const char*)SH + 32768 + (wn & 1) * 8192 + l15 * 128
                      + (((0 * 2 + koh + (wn >> 1) * 4) ^ l7) << 4) + kol * 8;
    const char* bB1 = (const char*)SH + 32768 + (wn & 1) * 8192 + l15 * 128
                      + (((1 * 2 + koh + (wn >> 1) * 4) ^ l7) << 4) + kol * 8;

#define LD_A(c, m, s) (*(const long long*)(((s) ? bA1 : bA0) + (c) * 16384 + (m) * 2048))
#define LD_B(c, n, s) (*(const long long*)(((s) ? bB1 : bB0) + (c) * 16384 + (n) * 2048))

#define BAR() __builtin_amdgcn_s_barrier()
#define VMC2() asm volatile("s_waitcnt vmcnt(2)" ::: "memory")
#define VMC0() asm volatile("s_waitcnt vmcnt(0)" ::: "memory")

    f32x4 acc[8][4];
    #pragma unroll
    for (int m = 0; m < 8; ++m)
        #pragma unroll
        for (int n = 0; n < 4; ++n)
            acc[m][n] = (f32x4){0.f, 0.f, 0.f, 0.f};

    long long bfr[4][2];
    long long fa0, fa1, fa2, fa3, fa4, fa5, fa6, fa7;

#define LDA_H(c, h) { fa0 = LD_A(c, 4*(h)+0, 0); fa1 = LD_A(c, 4*(h)+0, 1);       \
                      fa2 = LD_A(c, 4*(h)+1, 0); fa3 = LD_A(c, 4*(h)+1, 1);       \
                      fa4 = LD_A(c, 4*(h)+2, 0); fa5 = LD_A(c, 4*(h)+2, 1);       \
                      fa6 = LD_A(c, 4*(h)+3, 0); fa7 = LD_A(c, 4*(h)+3, 1); }
#define LDB_ALL(c) { _Pragma("unroll") for (int n = 0; n < 4; ++n) {              \
                       bfr[n][0] = LD_B(c, n, 0); bfr[n][1] = LD_B(c, n, 1); } }
#define MFMA_H(h) { __builtin_amdgcn_s_setprio(1);                                \
    _Pragma("unroll") for (int n = 0; n < 4; ++n) {                               \
      acc[4*(h)+0][n] = __builtin_amdgcn_mfma_f32_16x16x32_fp8_fp8(bfr[n][0], fa0, acc[4*(h)+0][n], 0,0,0); \
      acc[4*(h)+0][n] = __builtin_amdgcn_mfma_f32_16x16x32_fp8_fp8(bfr[n][1], fa1, acc[4*(h)+0][n], 0,0,0); \
      acc[4*(h)+1][n] = __builtin_amdgcn_mfma_f32_16x16x32_fp8_fp8(bfr[n][0], fa2, acc[4*(h)+1][n], 0,0,0); \
      acc[4*(h)+1][n] = __builtin_amdgcn_mfma_f32_16x16x32_fp8_fp8(bfr[n][1], fa3, acc[4*(h)+1][n], 0,0,0); \
      acc[4*(h)+2][n] = __builtin_amdgcn_mfma_f32_16x16x32_fp8_fp8(bfr[n][0], fa4, acc[4*(h)+2][n], 0,0,0); \
      acc[4*(h)+2][n] = __builtin_amdgcn_mfma_f32_16x16x32_fp8_fp8(bfr[n][1], fa5, acc[4*(h)+2][n], 0,0,0); \
      acc[4*(h)+3][n] = __builtin_amdgcn_mfma_f32_16x16x32_fp8_fp8(bfr[n][0], fa6, acc[4*(h)+3][n], 0,0,0); \
      acc[4*(h)+3][n] = __builtin_amdgcn_mfma_f32_16x16x32_fp8_fp8(bfr[n][1], fa7, acc[4*(h)+3][n], 0,0,0); } \
    __builtin_amdgcn_s_setprio(0); }

    STAGE_B(gB, 0, 0, 0); STAGE_B(gB, 0, 1, 0);
    STAGE_A(gA, 0, 0, 0); STAGE_A(gA, 0, 1, 0);
    STAGE_B(gB, 1, 0, 1); STAGE_B(gB, 1, 1, 1);
    VMC2();
    BAR();

    const unsigned char* gAt = gA;
    const unsigned char* gBt = gB;
    for (int i = 0; i < 4; ++i) {
        const bool s23 = (i < 3);

        LDA_H(0, 0); LDB_ALL(0);
        STAGE_A(gAt, 1, 0, 1); STAGE_A(gAt, 1, 1, 1);
        BAR(); MFMA_H(0); BAR();

        LDA_H(0, 1);
        if (s23) { STAGE_B(gBt, 0, 0, 2); STAGE_B(gBt, 0, 1, 2); }
        BAR(); MFMA_H(1);
        if (s23) { VMC2(); } else { VMC0(); }
        BAR();

        LDA_H(1, 0); LDB_ALL(1);
        if (s23) { STAGE_A(gAt, 0, 0, 2); STAGE_A(gAt, 0, 1, 2); }
        BAR(); MFMA_H(0); BAR();

        LDA_H(1, 1);
        if (s23) { STAGE_B(gBt, 1, 0, 3); STAGE_B(gBt, 1, 1, 3); }
        BAR(); MFMA_H(1);
        if (s23) { VMC2(); }
        BAR();

        gAt += 128; gBt += 128;
    }

    {
        const int q  = lane >> 4;
        const int tr = wr * 128 + (lane & 15);
        #pragma unroll
        for (int n = 0; n < 4; ++n) {
            float4 bb = *(const float4*)(bias + n0 + wn * 64 + n * 16 + q * 4);
            const int g16 = wn * 4 + n;
            #pragma unroll
            for (int m = 0; m < 8; ++m) {
                const int trm = tr + m * 16;
                unsigned int pk = __builtin_amdgcn_cvt_pk_fp8_f32(
                    acc[m][n][0] + 16.f * bb.x, acc[m][n][1] + 16.f * bb.y, 0u, false);
                pk = __builtin_amdgcn_cvt_pk_fp8_f32(
                    acc[m][n][2] + 16.f * bb.z, acc[m][n][3] + 16.f * bb.w, pk, true);
                *(unsigned int*)(SH + trm * 256 + ((g16 ^ (trm & 15)) << 4) + q * 4) = pk;
            }
        }
        BAR();
        #pragma unroll
        for (int it = 0; it < 8; ++it) {
            const int f = it * 512 + tid;
            const int rr = f >> 4, gg = f & 15;
            uint4 v = *(const uint4*)(SH + rr * 256 + ((gg ^ (rr & 15)) << 4));
            *(uint4*)(C + (size_t)(row0 + rr) * 4096 + gg * 16 + n0) = v;
        }
    }
#undef STAGE_A
#undef STAGE_B
#undef LD_A
#undef LD_B
}

// ---------------- kernel 3: fp8-MFMA scores + softmax + pb-partials (dual-acc) -------
__global__ __launch_bounds__(256) void mfscores(const unsigned char* __restrict__ Q,
                                                const unsigned char* __restrict__ K,
                                                float* __restrict__ P,
                                                float* __restrict__ pbpart)
{
    __shared__ float Pl[8 * 64];
    const int b = blockIdx.x, lc = blockIdx.y;       // (8, 64)
    const int tid = threadIdx.x, lane = tid & 63, w = tid >> 6;
    const int l0 = lc * 8;

    const int colr = lane & 15;
    const int ko   = lane >> 4;
    const int la   = l0 + w * 2 + (colr >> 3);
    const int hh   = colr & 7;
    const unsigned char* qrow = Q + (size_t)(b * 512 + la) * 4096 + hh * 512 + ko * 8;
    const unsigned char* krow = K + (size_t)(b * 512 + la) * 4096 + hh * 512 + ko * 8;

    // two independent accumulator chains (even/odd k-tiles) -> half the MFMA dep chain
    f32x4 acc0 = (f32x4){0.f, 0.f, 0.f, 0.f};
    f32x4 acc1 = (f32x4){0.f, 0.f, 0.f, 0.f};
    #pragma unroll
    for (int kt = 0; kt < 8; ++kt) {
        long long a0 = *(const long long*)(qrow + (2 * kt) * 32);
        long long b0 = *(const long long*)(krow + (2 * kt) * 32);
        long long a1 = *(const long long*)(qrow + (2 * kt + 1) * 32);
        long long b1 = *(const long long*)(krow + (2 * kt + 1) * 32);
        acc0 = __builtin_amdgcn_mfma_f32_16x16x32_fp8_fp8(a0, b0, acc0, 0, 0, 0);
        acc1 = __builtin_amdgcn_mfma_f32_16x16x32_fp8_fp8(a1, b1, acc1, 0, 0, 0);
    }

    const int lpr = ko >> 1;
    const int lpc = (lane >> 3) & 1;
    #pragma unroll
    for (int r = 0; r < 4; ++r) {
        float s = (acc0[r] + acc1[r]) * 1.7263349150062e-4f;   // 1/(256*sqrt(512))
        float m = s;
        m = fmaxf(m, __shfl_xor(m, 1));
        m = fmaxf(m, __shfl_xor(m, 2));
        m = fmaxf(m, __shfl_xor(m, 4));
        float e = __expf(s - m);
        float ss = e;
        ss += __shfl_xor(ss, 1);
        ss += __shfl_xor(ss, 2);
        ss += __shfl_xor(ss, 4);
        float p = e / ss + 63.875f;               // fold uniform part
        if (lpr == lpc)
            Pl[(w * 2 + lpr) * 64 + ((ko & 1) * 4 + r) * 8 + (lane & 7)] = p;
    }
    __syncthreads();

    {
        const int l = tid >> 5, off = (tid & 31) * 2;
        float2 v = *(const float2*)&Pl[l * 64 + off];
        *(float2*)(P + (size_t)(b * 512 + l0 + l) * 64 + off) = v;
    }
    if (tid < 64) {
        float s = 0.f;
        #pragma unroll
        for (int l = 0; l < 8; ++l) s += Pl[l * 64 + tid];
        pbpart[((size_t)b * 64 + lc) * 64 + tid] = s;
    }
}

// ---------------- kernel 4: ypart[lc,b,hg,d] = sum_{l in 64-chunk} P' * Xv -----------
__global__ __launch_bounds__(256) void ykern(const float* __restrict__ P,
                                             const float* __restrict__ Xv,
                                             float* __restrict__ ypart)
{
    __shared__ float Pl[64 * 64];
    __shared__ float Xl[64 * 64];
    const int b = blockIdx.x, dt = blockIdx.y, lc = blockIdx.z;   // (8, 8, 8)
    const int tid = threadIdx.x;
    const int tm = tid & 15, te = tid >> 4;

    const float* Pg = P + ((size_t)b * 512 + lc * 64) * 64;
    #pragma unroll
    for (int i = 0; i < 4; ++i)
        *(float4*)&Pl[(i * 256 + tid) * 4] = *(const float4*)(Pg + (size_t)(i * 256 + tid) * 4);
    const float* Xg = Xv + ((size_t)b * 512 + lc * 64) * 512 + dt * 64;
    #pragma unroll
    for (int i = 0; i < 4; ++i) {
        int flat = i * 256 + tid;            // 1024 float4 = 64 rows x 16
        int r = flat >> 4, q = flat & 15;
        *(float4*)&Xl[r * 64 + q * 4] = *(const float4*)(Xg + (size_t)r * 512 + q * 4);
    }
    __syncthreads();

    float4 acc[4];
    #pragma unroll
    for (int i = 0; i < 4; ++i) acc[i] = make_float4(0.f, 0.f, 0.f, 0.f);

    for (int l = 0; l < 64; ++l) {
        float4 pv = *(const float4*)&Pl[l * 64 + tm * 4];
        float4 xv = *(const float4*)&Xl[l * 64 + te * 4];
        acc[0].x += pv.x * xv.x; acc[0].y += pv.x * xv.y; acc[0].z += pv.x * xv.z; acc[0].w += pv.x * xv.w;
        acc[1].x += pv.y * xv.x; acc[1].y += pv.y * xv.y; acc[1].z += pv.y * xv.z; acc[1].w += pv.y * xv.w;
        acc[2].x += pv.z * xv.x; acc[2].y += pv.z * xv.y; acc[2].z += pv.z * xv.z; acc[2].w += pv.z * xv.w;
        acc[3].x += pv.w * xv.x; acc[3].y += pv.w * xv.y; acc[3].z += pv.w * xv.z; acc[3].w += pv.w * xv.w;
    }
    #pragma unroll
    for (int i = 0; i < 4; ++i)
        *(float4*)&ypart[(((size_t)lc * 8 + b) * 64 + tm * 4 + i) * 512 + dt * 64 + te * 4] = acc[i];
}

// ---------------- kernel 5: split-K vgemm (sums 8 ypart slices in A-stage) -----------
__global__ __launch_bounds__(256) void vgemm(const float* __restrict__ ypart,
                                             const float* __restrict__ Wv,
                                             float* __restrict__ partial)
{
    __shared__ float Al[64 * 64];
    __shared__ float Bl[64 * 64];
    const int et = blockIdx.x, kc = blockIdx.y;
    const int g = kc >> 3, d0 = (kc & 7) * 64, e0 = et * 64;
    const int tid = threadIdx.x;
    const int tm = tid & 15, te = tid >> 4;

    #pragma unroll
    for (int i = 0; i < 4; ++i) {
        int flat = i * 256 + tid;
        int bh = flat >> 4, dq = flat & 15;
        int yrow = (bh >> 3) * 64 + (bh & 7) * 8 + g;
        size_t base = ((size_t)(yrow >> 6) * 64 + (yrow & 63)) * 512 + d0 + dq * 4;
        float4 v = *(const float4*)(ypart + base);
        #pragma unroll
        for (int lc = 1; lc < 8; ++lc) {
            float4 t = *(const float4*)(ypart + (size_t)lc * 262144 + base);
            v.x += t.x; v.y += t.y; v.z += t.z; v.w += t.w;
        }
        *(float4*)&Al[bh * 64 + ((dq ^ (bh >> 2)) << 2)] = v;
    }
    #pragma unroll
    for (int i = 0; i < 4; ++i) {
        int flat = i * 256 + tid;
        int kk = flat >> 4, eq = flat & 15;
        *(float4*)&Bl[kk * 64 + eq * 4] =
            *(const float4*)(Wv + (size_t)(d0 + kk) * 4096 + g * 512 + e0 + eq * 4);
    }
    __syncthreads();

    float4 acc[4];
    #pragma unroll
    for (int j = 0; j < 4; ++j) acc[j] = make_float4(0.f, 0.f, 0.f, 0.f);

    for (int k = 0; k < 64; ++k) {
        float4 b4 = *(const float4*)&Bl[k * 64 + te * 4];
        const int gcol = (((k >> 2) ^ tm) << 2) + (k & 3);
        #pragma unroll
        for (int j = 0; j < 4; ++j) {
            float a = Al[(tm * 4 + j) * 64 + gcol];
            acc[j].x += a * b4.x; acc[j].y += a * b4.y;
            acc[j].z += a * b4.z; acc[j].w += a * b4.w;
        }
    }
    #pragma unroll
    for (int j = 0; j < 4; ++j)
        *(float4*)&partial[(size_t)kc * 32768 + (tm * 4 + j) * 512 + e0 + te * 4] = acc[j];
}

// ---------------- kernel 6: finalize: out = sum_kc partial + sum_g c*bv --------------
__global__ __launch_bounds__(256) void finalize(const float* __restrict__ partial,
                                                const float* __restrict__ pbpart,
                                                const float* __restrict__ bv,
                                                float* __restrict__ out)
{
    __shared__ float red[64];
    __shared__ float csh[8];
    const int blk = blockIdx.x;          // 128 blocks: (b,h) x half-e
    const int tid = threadIdx.x;
    const int b = blk >> 4, h = (blk >> 1) & 7;
    const int e = (blk & 1) * 256 + tid;

    if (tid < 64) {                      // parallel pb-scan: 64 lanes x 8 lc each
        const int g = tid >> 3, seg = tid & 7;
        float s = 0.f;
        #pragma unroll
        for (int j = 0; j < 8; ++j)
            s += pbpart[((size_t)b * 64 + seg * 8 + j) * 64 + h * 8 + g];
        red[tid] = s;
    }
    __syncthreads();
    if (tid < 8) {
        float s = 0.f;
        #pragma unroll
        for (int seg = 0; seg < 8; ++seg) s += red[tid * 8 + seg];
        csh[tid] = s;
    }
    __syncthreads();

    const int i = ((b * 8 + h) << 9) + e;
    float s = 0.f;
    #pragma unroll
    for (int kc = 0; kc < 64; ++kc) s += partial[(size_t)kc * 32768 + i];
    float bt = 0.f;
    #pragma unroll
    for (int g = 0; g < 8; ++g) bt += csh[g] * bv[g * 512 + e];
    out[i] = s + bt;
}

extern "C" void kernel_launch(void* const* d_in, const int* in_sizes, int n_in,
                              void* d_out, int out_size, void* d_ws, size_t ws_size,
                              hipStream_t stream)
{
    const float* queries = (const float*)d_in[0];
    const float* keys    = (const float*)d_in[1];
    const float* values  = (const float*)d_in[2];
    const float* Wq      = (const float*)d_in[3];
    const float* bq      = (const float*)d_in[4];
    const float* Wk      = (const float*)d_in[5];
    const float* bk      = (const float*)d_in[6];
    const float* Wv      = (const float*)d_in[7];
    const float* bv      = (const float*)d_in[8];

    unsigned char* xq  = (unsigned char*)d_ws;          // 2 MB each
    unsigned char* xk  = xq  + (1u << 21);
    unsigned char* wtq = xk  + (1u << 21);
    unsigned char* wtk = wtq + (1u << 21);
    unsigned char* Q   = wtk + (1u << 21);              // 16 MB each
    unsigned char* Kb  = Q   + (1u << 24);
    float* P      = (float*)(Kb + (1u << 24));
    float* pbpart = P + 262144;
    float* ypart  = pbpart + 32768;                     // 8 x 262144 floats
    float* part   = ypart + 8 * 262144;

    prep<<<dim3(2048, 1, 4), 256, 0, stream>>>(queries, keys, xq, xk, Wq, Wk, wtq, wtk);
    gemm_bt256<<<dim3(16, 16, 2), 512, 0, stream>>>(xq, xk, wtq, wtk, bq, bk, Q, Kb);
    mfscores<<<dim3(8, 64), 256, 0, stream>>>(Q, Kb, P, pbpart);
    ykern<<<dim3(8, 8, 8), 256, 0, stream>>>(P, values, ypart);
    vgemm<<<dim3(8, 64), 256, 0, stream>>>(ypart, Wv, part);
    finalize<<<dim3(128), 256, 0, stream>>>(part, pbpart, bv, (float*)d_out);
}

// Round 15
// 77.717 us; speedup vs baseline: 1.0728x; 1.0728x over previous
//
#include <hip/hip_runtime.h>

// B=8, L=512, D=512, H=8. Q/K GEMMs: M=4096, N=4096, K=512 -- fp8-e4m3 MFMA.
// R15: mfscores now LDS-staged (coalesced 16B/lane global loads; hh-XOR 16B-granule
// swizzle -> 2-way-free LDS reads). ykern/vgemm reverted to R11 4-slice (R14's 8-slice
// doubled ypart traffic). gemm = R13 4-phase (invariant across schedules; ~905 TF eff).
// V path (all f32): P' = softmax + 63.875; Y = sum_l P'*Xv; out = Y @ Wv + c*bv.

using f32x4 = __attribute__((ext_vector_type(4))) float;

#define GLOAD16(gp, lp) __builtin_amdgcn_global_load_lds( \
    (const __attribute__((address_space(1))) unsigned int*)(gp), \
    (__attribute__((address_space(3))) unsigned int*)(lp), 16, 0, 0)

// ---------------- kernel 1: prep = convert Xq/Xk -> fp8 (z=0,1); transpose W*16 -> fp8 (z=2,3)
__global__ __launch_bounds__(256) void prep(
    const float* __restrict__ x0, const float* __restrict__ x1,
    unsigned char* __restrict__ o0, unsigned char* __restrict__ o1,
    const float* __restrict__ w0, const float* __restrict__ w1,
    unsigned char* __restrict__ t0, unsigned char* __restrict__ t1)
{
    const int z = blockIdx.z;
    if (z < 2) {
        const float* src = (z == 0) ? x0 : x1;
        unsigned char* dst = (z == 0) ? o0 : o1;
        int i = (blockIdx.x * 256 + threadIdx.x) * 8;
        if (i < 2097152) {
            float4 a = *(const float4*)(src + i);
            float4 b = *(const float4*)(src + i + 4);
            uint2 u;
            u.x = __builtin_amdgcn_cvt_pk_fp8_f32(a.x, a.y, 0u, false);
            u.x = __builtin_amdgcn_cvt_pk_fp8_f32(a.z, a.w, u.x, true);
            u.y = __builtin_amdgcn_cvt_pk_fp8_f32(b.x, b.y, 0u, false);
            u.y = __builtin_amdgcn_cvt_pk_fp8_f32(b.z, b.w, u.y, true);
            *(uint2*)(dst + i) = u;
        }
    } else {
        const float* W = (z == 2) ? w0 : w1;
        unsigned char* T = (z == 2) ? t0 : t1;
        __shared__ float tile[32][33];
        const int n0 = (blockIdx.x & 127) * 32, k0 = (blockIdx.x >> 7) * 32;
        const int tx = threadIdx.x & 31, ty = threadIdx.x >> 5;   // (32, 8)
        #pragma unroll
        for (int j = 0; j < 32; j += 8)
            tile[ty + j][tx] = W[(size_t)(k0 + ty + j) * 4096 + n0 + tx];
        __syncthreads();
        const int n = ty * 4 + (tx >> 3), kq = tx & 7;
        unsigned int pk = __builtin_amdgcn_cvt_pk_fp8_f32(
            16.f * tile[kq * 4 + 0][n], 16.f * tile[kq * 4 + 1][n], 0u, false);
        pk = __builtin_amdgcn_cvt_pk_fp8_f32(
            16.f * tile[kq * 4 + 2][n], 16.f * tile[kq * 4 + 3][n], pk, true);
        *(unsigned int*)(T + (size_t)(n0 + n) * 512 + k0 + kq * 4) = pk;
    }
}

// ---------------- kernel 2: 256^2 FP8 GEMM, 64KB row-pair-packed LDS, 4-phase --------
__global__ __launch_bounds__(512) void gemm_bt256(
    const unsigned char* __restrict__ a0, const unsigned char* __restrict__ a1,
    const unsigned char* __restrict__ w0, const unsigned char* __restrict__ w1,
    const float* __restrict__ b0, const float* __restrict__ b1,
    unsigned char* __restrict__ c0, unsigned char* __restrict__ c1)
{
    const unsigned char* A;  const unsigned char* Bt; const float* bias; unsigned char* C;
    if (blockIdx.z == 0) { A = a0; Bt = w0; bias = b0; C = c0; }
    else                 { A = a1; Bt = w1; bias = b1; C = c1; }

    __shared__ __align__(16) unsigned char SH[65536];

    const int tid  = threadIdx.x;
    const int lane = tid & 63;
    const int wid  = tid >> 6;
    const int wr   = wid >> 2;
    const int wn   = wid & 3;
    const int linb = blockIdx.y * 16 + blockIdx.x;
    const int swz  = (linb & 7) * 32 + (linb >> 3);
    const int bx   = (swz >> 6) * 4 + (swz & 3);
    const int by   = (swz >> 2) & 15;
    const int row0 = by * 256;
    const int n0   = bx * 256;

    const int lgs = (tid & 7) ^ ((tid >> 3) & 7);
    const int shi = lgs >> 2, slo = lgs & 3;
    const int srow0 = (tid >> 3) + shi * 128;
    const unsigned char* gA = A  + (size_t)(row0 + srow0) * 512 + slo * 16;
    const unsigned char* gB = Bt + (size_t)(n0   + srow0) * 512 + slo * 16;

#define STAGE_A(gp, buf, c, trel)                                                 \
    GLOAD16((gp) + (c) * (64 * 512) + (trel) * 64,                                \
            SH + (buf) * 16384 + (c) * 8192 + wid * 1024)
#define STAGE_B(gp, buf, c, trel)                                                 \
    GLOAD16((gp) + (c) * (64 * 512) + (trel) * 64,                                \
            SH + 32768 + (buf) * 16384 + (c) * 8192 + wid * 1024)

    const int l7 = lane & 7, koh = lane >> 5, kol = (lane >> 4) & 1, l15 = lane & 15;
    const char* bA0 = (const char*)SH + l15 * 128 + (((0 * 2 + koh + wr * 4) ^ l7) << 4) + kol * 8;
    const char* bA1 = (const char*)SH + l15 * 128 + (((1 * 2 + koh + wr * 4) ^ l7) << 4) + kol * 8;
    const char* bB0 = (const char*)SH + 32768 + (wn & 1) * 8192 + l15 * 128
                      + (((0 * 2 + koh + (wn >> 1) * 4) ^ l7) << 4) + kol * 8;
    const char* bB1 = (const char*)SH + 32768 + (wn & 1) * 8192 + l15 * 128
                      + (((1 * 2 + koh + (wn >> 1) * 4) ^ l7) << 4) + kol * 8;

#define LD_A(c, m, s) (*(const long long*)(((s) ? bA1 : bA0) + (c) * 16384 + (m) * 2048))
#define LD_B(c, n, s) (*(const long long*)(((s) ? bB1 : bB0) + (c) * 16384 + (n) * 2048))

#define BAR() __builtin_amdgcn_s_barrier()
#define VMC2() asm volatile("s_waitcnt vmcnt(2)" ::: "memory")
#define VMC0() asm volatile("s_waitcnt vmcnt(0)" ::: "memory")

    f32x4 acc[8][4];
    #pragma unroll
    for (int m = 0; m < 8; ++m)
        #pragma unroll
        for (int n = 0; n < 4; ++n)
            acc[m][n] = (f32x4){0.f, 0.f, 0.f, 0.f};

    long long bfr[4][2];
    long long fa0, fa1, fa2, fa3, fa4, fa5, fa6, fa7;

#define LDA_H(c, h) { fa0 = LD_A(c, 4*(h)+0, 0); fa1 = LD_A(c, 4*(h)+0, 1);       \
                      fa2 = LD_A(c, 4*(h)+1, 0); fa3 = LD_A(c, 4*(h)+1, 1);       \
                      fa4 = LD_A(c, 4*(h)+2, 0); fa5 = LD_A(c, 4*(h)+2, 1);       \
                      fa6 = LD_A(c, 4*(h)+3, 0); fa7 = LD_A(c, 4*(h)+3, 1); }
#define LDB_ALL(c) { _Pragma("unroll") for (int n = 0; n < 4; ++n) {              \
                       bfr[n][0] = LD_B(c, n, 0); bfr[n][1] = LD_B(c, n, 1); } }
#define MFMA_H(h) { __builtin_amdgcn_s_setprio(1);                                \
    _Pragma("unroll") for (int n = 0; n < 4; ++n) {                               \
      acc[4*(h)+0][n] = __builtin_amdgcn_mfma_f32_16x16x32_fp8_fp8(bfr[n][0], fa0, acc[4*(h)+0][n], 0,0,0); \
      acc[4*(h)+0][n] = __builtin_amdgcn_mfma_f32_16x16x32_fp8_fp8(bfr[n][1], fa1, acc[4*(h)+0][n], 0,0,0); \
      acc[4*(h)+1][n] = __builtin_amdgcn_mfma_f32_16x16x32_fp8_fp8(bfr[n][0], fa2, acc[4*(h)+1][n], 0,0,0); \
      acc[4*(h)+1][n] = __builtin_amdgcn_mfma_f32_16x16x32_fp8_fp8(bfr[n][1], fa3, acc[4*(h)+1][n], 0,0,0); \
      acc[4*(h)+2][n] = __builtin_amdgcn_mfma_f32_16x16x32_fp8_fp8(bfr[n][0], fa4, acc[4*(h)+2][n], 0,0,0); \
      acc[4*(h)+2][n] = __builtin_amdgcn_mfma_f32_16x16x32_fp8_fp8(bfr[n][1], fa5, acc[4*(h)+2][n], 0,0,0); \
      acc[4*(h)+3][n] = __builtin_amdgcn_mfma_f32_16x16x32_fp8_fp8(bfr[n][0], fa6, acc[4*(h)+3][n], 0,0,0); \
      acc[4*(h)+3][n] = __builtin_amdgcn_mfma_f32_16x16x32_fp8_fp8(bfr[n][1], fa7, acc[4*(h)+3][n], 0,0,0); } \
    __builtin_amdgcn_s_setprio(0); }

    STAGE_B(gB, 0, 0, 0); STAGE_B(gB, 0, 1, 0);
    STAGE_A(gA, 0, 0, 0); STAGE_A(gA, 0, 1, 0);
    STAGE_B(gB, 1, 0, 1); STAGE_B(gB, 1, 1, 1);
    VMC2();
    BAR();

    const unsigned char* gAt = gA;
    const unsigned char* gBt = gB;
    for (int i = 0; i < 4; ++i) {
        const bool s23 = (i < 3);

        LDA_H(0, 0); LDB_ALL(0);
        STAGE_A(gAt, 1, 0, 1); STAGE_A(gAt, 1, 1, 1);
        BAR(); MFMA_H(0); BAR();

        LDA_H(0, 1);
        if (s23) { STAGE_B(gBt, 0, 0, 2); STAGE_B(gBt, 0, 1, 2); }
        BAR(); MFMA_H(1);
        if (s23) { VMC2(); } else { VMC0(); }
        BAR();

        LDA_H(1, 0); LDB_ALL(1);
        if (s23) { STAGE_A(gAt, 0, 0, 2); STAGE_A(gAt, 0, 1, 2); }
        BAR(); MFMA_H(0); BAR();

        LDA_H(1, 1);
        if (s23) { STAGE_B(gBt, 1, 0, 3); STAGE_B(gBt, 1, 1, 3); }
        BAR(); MFMA_H(1);
        if (s23) { VMC2(); }
        BAR();

        gAt += 128; gBt += 128;
    }

    {
        const int q  = lane >> 4;
        const int tr = wr * 128 + (lane & 15);
        #pragma unroll
        for (int n = 0; n < 4; ++n) {
            float4 bb = *(const float4*)(bias + n0 + wn * 64 + n * 16 + q * 4);
            const int g16 = wn * 4 + n;
            #pragma unroll
            for (int m = 0; m < 8; ++m) {
                const int trm = tr + m * 16;
                unsigned int pk = __builtin_amdgcn_cvt_pk_fp8_f32(
                    acc[m][n][0] + 16.f * bb.x, acc[m][n][1] + 16.f * bb.y, 0u, false);
                pk = __builtin_amdgcn_cvt_pk_fp8_f32(
                    acc[m][n][2] + 16.f * bb.z, acc[m][n][3] + 16.f * bb.w, pk, true);
                *(unsigned int*)(SH + trm * 256 + ((g16 ^ (trm & 15)) << 4) + q * 4) = pk;
            }
        }
        BAR();
        #pragma unroll
        for (int it = 0; it < 8; ++it) {
            const int f = it * 512 + tid;
            const int rr = f >> 4, gg = f & 15;
            uint4 v = *(const uint4*)(SH + rr * 256 + ((gg ^ (rr & 15)) << 4));
            *(uint4*)(C + (size_t)(row0 + rr) * 4096 + gg * 16 + n0) = v;
        }
    }
#undef STAGE_A
#undef STAGE_B
#undef LD_A
#undef LD_B
}

// ---------------- kernel 3: LDS-staged fp8-MFMA scores + softmax + pb-partials -------
// Stage 8 Q-rows + 8 K-rows (64KB) coalesced, 16B-granule XOR-swizzled (g16 ^= hh).
__global__ __launch_bounds__(256) void mfscores(const unsigned char* __restrict__ Q,
                                                const unsigned char* __restrict__ K,
                                                float* __restrict__ P,
                                                float* __restrict__ pbpart)
{
    __shared__ __align__(16) unsigned char Qs[32768];
    __shared__ __align__(16) unsigned char Ks[32768];
    __shared__ float Pl[8 * 64];
    const int b = blockIdx.x, lc = blockIdx.y;       // (8, 64)
    const int tid = threadIdx.x, lane = tid & 63, w = tid >> 6;
    const int l0 = lc * 8;

    // ---- coalesced staging: row i, bytes tid*16..+15 -> swizzled LDS ----
    {
        const unsigned char* Qg = Q + (size_t)(b * 512 + l0) * 4096;
        const unsigned char* Kg = K + (size_t)(b * 512 + l0) * 4096;
        const int hhs = tid >> 5;                    // dest chunk
        const int dst = hhs * 512 + (((tid & 31) ^ hhs) << 4);
        #pragma unroll
        for (int i = 0; i < 8; ++i) {
            *(uint4*)(Qs + i * 4096 + dst) = *(const uint4*)(Qg + i * 4096 + tid * 16);
            *(uint4*)(Ks + i * 4096 + dst) = *(const uint4*)(Kg + i * 4096 + tid * 16);
        }
    }
    __syncthreads();

    const int colr = lane & 15;
    const int ko   = lane >> 4;
    const int lrow = w * 2 + (colr >> 3);            // local row 0..7
    const int hh   = colr & 7;
    const unsigned char* qb = Qs + lrow * 4096 + hh * 512 + (ko & 1) * 8;
    const unsigned char* kb = Ks + lrow * 4096 + hh * 512 + (ko & 1) * 8;
    const int koh = ko >> 1;

    // dual accumulator chains (even/odd k-tiles)
    f32x4 acc0 = (f32x4){0.f, 0.f, 0.f, 0.f};
    f32x4 acc1 = (f32x4){0.f, 0.f, 0.f, 0.f};
    #pragma unroll
    for (int kt = 0; kt < 8; ++kt) {
        const int s0 = (((2 * (2 * kt)     + koh) ^ hh) << 4);
        const int s1 = (((2 * (2 * kt + 1) + koh) ^ hh) << 4);
        long long a0 = *(const long long*)(qb + s0);
        long long b0 = *(const long long*)(kb + s0);
        long long a1 = *(const long long*)(qb + s1);
        long long b1 = *(const long long*)(kb + s1);
        acc0 = __builtin_amdgcn_mfma_f32_16x16x32_fp8_fp8(a0, b0, acc0, 0, 0, 0);
        acc1 = __builtin_amdgcn_mfma_f32_16x16x32_fp8_fp8(a1, b1, acc1, 0, 0, 0);
    }

    const int lpr = ko >> 1;
    const int lpc = (lane >> 3) & 1;
    #pragma unroll
    for (int r = 0; r < 4; ++r) {
        float s = (acc0[r] + acc1[r]) * 1.7263349150062e-4f;   // 1/(256*sqrt(512))
        float m = s;
        m = fmaxf(m, __shfl_xor(m, 1));
        m = fmaxf(m, __shfl_xor(m, 2));
        m = fmaxf(m, __shfl_xor(m, 4));
        float e = __expf(s - m);
        float ss = e;
        ss += __shfl_xor(ss, 1);
        ss += __shfl_xor(ss, 2);
        ss += __shfl_xor(ss, 4);
        float p = e / ss + 63.875f;               // fold uniform part
        if (lpr == lpc)
            Pl[(w * 2 + lpr) * 64 + ((ko & 1) * 4 + r) * 8 + (lane & 7)] = p;
    }
    __syncthreads();

    {
        const int l = tid >> 5, off = (tid & 31) * 2;
        float2 v = *(const float2*)&Pl[l * 64 + off];
        *(float2*)(P + (size_t)(b * 512 + l0 + l) * 64 + off) = v;
    }
    if (tid < 64) {
        float s = 0.f;
        #pragma unroll
        for (int l = 0; l < 8; ++l) s += Pl[l * 64 + tid];
        pbpart[((size_t)b * 64 + lc) * 64 + tid] = s;
    }
}

// ---------------- kernel 4: ypart[lc,b,hg,d] = sum_{l in 128-chunk} P' * Xv ----------
__global__ __launch_bounds__(256) void ykern(const float* __restrict__ P,
                                             const float* __restrict__ Xv,
                                             float* __restrict__ ypart)
{
    __shared__ float Pl[128 * 64];
    __shared__ float Xl[128 * 64];
    const int b = blockIdx.x, dt = blockIdx.y, lc = blockIdx.z;   // (8, 8, 4)
    const int tid = threadIdx.x;
    const int tm = tid & 15, te = tid >> 4;

    const float* Pg = P + ((size_t)b * 512 + lc * 128) * 64;
    #pragma unroll
    for (int i = 0; i < 8; ++i)
        *(float4*)&Pl[(i * 256 + tid) * 4] = *(const float4*)(Pg + (size_t)(i * 256 + tid) * 4);
    const float* Xg = Xv + ((size_t)b * 512 + lc * 128) * 512 + dt * 64;
    #pragma unroll
    for (int i = 0; i < 8; ++i) {
        int flat = i * 256 + tid;
        int r = flat >> 4, q = flat & 15;
        *(float4*)&Xl[r * 64 + q * 4] = *(const float4*)(Xg + (size_t)r * 512 + q * 4);
    }
    __syncthreads();

    float4 acc[4];
    #pragma unroll
    for (int i = 0; i < 4; ++i) acc[i] = make_float4(0.f, 0.f, 0.f, 0.f);

    for (int l = 0; l < 128; ++l) {
        float4 pv = *(const float4*)&Pl[l * 64 + tm * 4];
        float4 xv = *(const float4*)&Xl[l * 64 + te * 4];
        acc[0].x += pv.x * xv.x; acc[0].y += pv.x * xv.y; acc[0].z += pv.x * xv.z; acc[0].w += pv.x * xv.w;
        acc[1].x += pv.y * xv.x; acc[1].y += pv.y * xv.y; acc[1].z += pv.y * xv.z; acc[1].w += pv.y * xv.w;
        acc[2].x += pv.z * xv.x; acc[2].y += pv.z * xv.y; acc[2].z += pv.z * xv.z; acc[2].w += pv.z * xv.w;
        acc[3].x += pv.w * xv.x; acc[3].y += pv.w * xv.y; acc[3].z += pv.w * xv.z; acc[3].w += pv.w * xv.w;
    }
    #pragma unroll
    for (int i = 0; i < 4; ++i)
        *(float4*)&ypart[(((size_t)lc * 8 + b) * 64 + tm * 4 + i) * 512 + dt * 64 + te * 4] = acc[i];
}

// ---------------- kernel 5: split-K vgemm (sums 4 ypart slices in A-stage) -----------
__global__ __launch_bounds__(256) void vgemm(const float* __restrict__ ypart,
                                             const float* __restrict__ Wv,
                                             float* __restrict__ partial)
{
    __shared__ float Al[64 * 64];
    __shared__ float Bl[64 * 64];
    const int et = blockIdx.x, kc = blockIdx.y;
    const int g = kc >> 3, d0 = (kc & 7) * 64, e0 = et * 64;
    const int tid = threadIdx.x;
    const int tm = tid & 15, te = tid >> 4;

    #pragma unroll
    for (int i = 0; i < 4; ++i) {
        int flat = i * 256 + tid;
        int bh = flat >> 4, dq = flat & 15;
        int yrow = (bh >> 3) * 64 + (bh & 7) * 8 + g;
        size_t base = ((size_t)(yrow >> 6) * 64 + (yrow & 63)) * 512 + d0 + dq * 4;
        float4 v = *(const float4*)(ypart + base);
        #pragma unroll
        for (int lc = 1; lc < 4; ++lc) {
            float4 t = *(const float4*)(ypart + (size_t)lc * 262144 + base);
            v.x += t.x; v.y += t.y; v.z += t.z; v.w += t.w;
        }
        *(float4*)&Al[bh * 64 + ((dq ^ (bh >> 2)) << 2)] = v;
    }
    #pragma unroll
    for (int i = 0; i < 4; ++i) {
        int flat = i * 256 + tid;
        int kk = flat >> 4, eq = flat & 15;
        *(float4*)&Bl[kk * 64 + eq * 4] =
            *(const float4*)(Wv + (size_t)(d0 + kk) * 4096 + g * 512 + e0 + eq * 4);
    }
    __syncthreads();

    float4 acc[4];
    #pragma unroll
    for (int j = 0; j < 4; ++j) acc[j] = make_float4(0.f, 0.f, 0.f, 0.f);

    for (int k = 0; k < 64; ++k) {
        float4 b4 = *(const float4*)&Bl[k * 64 + te * 4];
        const int gcol = (((k >> 2) ^ tm) << 2) + (k & 3);
        #pragma unroll
        for (int j = 0; j < 4; ++j) {
            float a = Al[(tm * 4 + j) * 64 + gcol];
            acc[j].x += a * b4.x; acc[j].y += a * b4.y;
            acc[j].z += a * b4.z; acc[j].w += a * b4.w;
        }
    }
    #pragma unroll
    for (int j = 0; j < 4; ++j)
        *(float4*)&partial[(size_t)kc * 32768 + (tm * 4 + j) * 512 + e0 + te * 4] = acc[j];
}

// ---------------- kernel 6: finalize: out = sum_kc partial + sum_g c*bv --------------
__global__ __launch_bounds__(256) void finalize(const float* __restrict__ partial,
                                                const float* __restrict__ pbpart,
                                                const float* __restrict__ bv,
                                                float* __restrict__ out)
{
    __shared__ float red[64];
    __shared__ float csh[8];
    const int blk = blockIdx.x;          // 128 blocks: (b,h) x half-e
    const int tid = threadIdx.x;
    const int b = blk >> 4, h = (blk >> 1) & 7;
    const int e = (blk & 1) * 256 + tid;

    if (tid < 64) {                      // parallel pb-scan: 64 lanes x 8 lc each
        const int g = tid >> 3, seg = tid & 7;
        float s = 0.f;
        #pragma unroll
        for (int j = 0; j < 8; ++j)
            s += pbpart[((size_t)b * 64 + seg * 8 + j) * 64 + h * 8 + g];
        red[tid] = s;
    }
    __syncthreads();
    if (tid < 8) {
        float s = 0.f;
        #pragma unroll
        for (int seg = 0; seg < 8; ++seg) s += red[tid + seg * 8];
        csh[tid] = s;
    }
    __syncthreads();

    const int i = ((b * 8 + h) << 9) + e;
    float s = 0.f;
    #pragma unroll
    for (int kc = 0; kc < 64; ++kc) s += partial[(size_t)kc * 32768 + i];
    float bt = 0.f;
    #pragma unroll
    for (int g = 0; g < 8; ++g) bt += csh[g] * bv[g * 512 + e];
    out[i] = s + bt;
}

extern "C" void kernel_launch(void* const* d_in, const int* in_sizes, int n_in,
                              void* d_out, int out_size, void* d_ws, size_t ws_size,
                              hipStream_t stream)
{
    const float* queries = (const float*)d_in[0];
    const float* keys    = (const float*)d_in[1];
    const float* values  = (const float*)d_in[2];
    const float* Wq      = (const float*)d_in[3];
    const float* bq      = (const float*)d_in[4];
    const float* Wk      = (const float*)d_in[5];
    const float* bk      = (const float*)d_in[6];
    const float* Wv      = (const float*)d_in[7];
    const float* bv      = (const float*)d_in[8];

    unsigned char* xq  = (unsigned char*)d_ws;          // 2 MB each
    unsigned char* xk  = xq  + (1u << 21);
    unsigned char* wtq = xk  + (1u << 21);
    unsigned char* wtk = wtq + (1u << 21);
    unsigned char* Q   = wtk + (1u << 21);              // 16 MB each
    unsigned char* Kb  = Q   + (1u << 24);
    float* P      = (float*)(Kb + (1u << 24));
    float* pbpart = P + 262144;
    float* ypart  = pbpart + 32768;                     // 4 x 262144 floats
    float* part   = ypart + 4 * 262144;

    prep<<<dim3(2048, 1, 4), 256, 0, stream>>>(queries, keys, xq, xk, Wq, Wk, wtq, wtk);
    gemm_bt256<<<dim3(16, 16, 2), 512, 0, stream>>>(xq, xk, wtq, wtk, bq, bk, Q, Kb);
    mfscores<<<dim3(8, 64), 256, 0, stream>>>(Q, Kb, P, pbpart);
    ykern<<<dim3(8, 8, 4), 256, 0, stream>>>(P, values, ypart);
    vgemm<<<dim3(8, 64), 256, 0, stream>>>(ypart, Wv, part);
    finalize<<<dim3(128), 256, 0, stream>>>(part, pbpart, bv, (float*)d_out);
}

// Round 16
// 73.392 us; speedup vs baseline: 1.1360x; 1.0589x over previous
//
#include <hip/hip_runtime.h>

// B=8, L=512, D=512, H=8. Q/K GEMMs: M=4096, N=4096, K=512 -- fp8-e4m3 MFMA.
// R16: prep rebuilt -- 64x64 W-transpose tiles (float4 reads, LDS [64][67] 2-way-free,
// uint4 fp8 writes), X-convert 1 float4/thread (no idle blocks). gemm: setprio removed
// (m190: hurts lockstep GEMM). Everything else = R15.
// V path (all f32): P' = softmax + 63.875; Y = sum_l P'*Xv; out = Y @ Wv + c*bv.

using f32x4 = __attribute__((ext_vector_type(4))) float;

#define GLOAD16(gp, lp) __builtin_amdgcn_global_load_lds( \
    (const __attribute__((address_space(1))) unsigned int*)(gp), \
    (__attribute__((address_space(3))) unsigned int*)(lp), 16, 0, 0)

// ---------------- kernel 1: prep = convert Xq/Xk -> fp8 (z=0,1); transpose W*16 -> fp8 (z=2,3)
__global__ __launch_bounds__(256) void prep(
    const float* __restrict__ x0, const float* __restrict__ x1,
    unsigned char* __restrict__ o0, unsigned char* __restrict__ o1,
    const float* __restrict__ w0, const float* __restrict__ w1,
    unsigned char* __restrict__ t0, unsigned char* __restrict__ t1)
{
    const int z = blockIdx.z;
    if (z < 2) {
        const float* src = (z == 0) ? x0 : x1;
        unsigned char* dst = (z == 0) ? o0 : o1;
        int i = (blockIdx.x * 256 + threadIdx.x) * 4;      // 2048 blocks x 1024 f = 2M
        float4 a = *(const float4*)(src + i);
        unsigned int u = __builtin_amdgcn_cvt_pk_fp8_f32(a.x, a.y, 0u, false);
        u = __builtin_amdgcn_cvt_pk_fp8_f32(a.z, a.w, u, true);
        *(unsigned int*)(dst + i) = u;
    } else {
        if (blockIdx.x >= 512) return;                     // 8 k-tiles x 64 n-tiles
        const float* W = (z == 2) ? w0 : w1;
        unsigned char* T = (z == 2) ? t0 : t1;
        __shared__ float tile[64][67];                     // stride 67: 2-way banks both phases
        const int kt = blockIdx.x >> 6, nt = blockIdx.x & 63;
        const int k0 = kt * 64, n0 = nt * 64;
        const int tid = threadIdx.x;
        #pragma unroll
        for (int it = 0; it < 4; ++it) {
            int f = it * 256 + tid;                        // 1024 float4
            int r = f >> 4, c4 = f & 15;
            float4 v = *(const float4*)(W + (size_t)(k0 + r) * 4096 + n0 + c4 * 4);
            tile[r][c4 * 4 + 0] = v.x; tile[r][c4 * 4 + 1] = v.y;
            tile[r][c4 * 4 + 2] = v.z; tile[r][c4 * 4 + 3] = v.w;
        }
        __syncthreads();
        const int n = tid >> 2, kq = tid & 3;              // thread: one n, 16 k's
        unsigned int pk4[4];
        #pragma unroll
        for (int q = 0; q < 4; ++q) {
            const int kk = kq * 16 + q * 4;
            unsigned int pk = __builtin_amdgcn_cvt_pk_fp8_f32(
                16.f * tile[kk + 0][n], 16.f * tile[kk + 1][n], 0u, false);
            pk = __builtin_amdgcn_cvt_pk_fp8_f32(
                16.f * tile[kk + 2][n], 16.f * tile[kk + 3][n], pk, true);
            pk4[q] = pk;
        }
        *(uint4*)(T + (size_t)(n0 + n) * 512 + k0 + kq * 16) =
            make_uint4(pk4[0], pk4[1], pk4[2], pk4[3]);
    }
}

// ---------------- kernel 2: 256^2 FP8 GEMM, 64KB row-pair-packed LDS, 4-phase --------
__global__ __launch_bounds__(512) void gemm_bt256(
    const unsigned char* __restrict__ a0, const unsigned char* __restrict__ a1,
    const unsigned char* __restrict__ w0, const unsigned char* __restrict__ w1,
    const float* __restrict__ b0, const float* __restrict__ b1,
    unsigned char* __restrict__ c0, unsigned char* __restrict__ c1)
{
    const unsigned char* A;  const unsigned char* Bt; const float* bias; unsigned char* C;
    if (blockIdx.z == 0) { A = a0; Bt = w0; bias = b0; C = c0; }
    else                 { A = a1; Bt = w1; bias = b1; C = c1; }

    __shared__ __align__(16) unsigned char SH[65536];

    const int tid  = threadIdx.x;
    const int lane = tid & 63;
    const int wid  = tid >> 6;
    const int wr   = wid >> 2;
    const int wn   = wid & 3;
    const int linb = blockIdx.y * 16 + blockIdx.x;
    const int swz  = (linb & 7) * 32 + (linb >> 3);
    const int bx   = (swz >> 6) * 4 + (swz & 3);
    const int by   = (swz >> 2) & 15;
    const int row0 = by * 256;
    const int n0   = bx * 256;

    const int lgs = (tid & 7) ^ ((tid >> 3) & 7);
    const int shi = lgs >> 2, slo = lgs & 3;
    const int srow0 = (tid >> 3) + shi * 128;
    const unsigned char* gA = A  + (size_t)(row0 + srow0) * 512 + slo * 16;
    const unsigned char* gB = Bt + (size_t)(n0   + srow0) * 512 + slo * 16;

#define STAGE_A(gp, buf, c, trel)                                                 \
    GLOAD16((gp) + (c) * (64 * 512) + (trel) * 64,                                \
            SH + (buf) * 16384 + (c) * 8192 + wid * 1024)
#define STAGE_B(gp, buf, c, trel)                                                 \
    GLOAD16((gp) + (c) * (64 * 512) + (trel) * 64,                                \
            SH + 32768 + (buf) * 16384 + (c) * 8192 + wid * 1024)

    const int l7 = lane & 7, koh = lane >> 5, kol = (lane >> 4) & 1, l15 = lane & 15;
    const char* bA0 = (const char*)SH + l15 * 128 + (((0 * 2 + koh + wr * 4) ^ l7) << 4) + kol * 8;
    const char* bA1 = (const char*)SH + l15 * 128 + (((1 * 2 + koh + wr * 4) ^ l7) << 4) + kol * 8;
    const char* bB0 = (const char*)SH + 32768 + (wn & 1) * 8192 + l15 * 128
                      + (((0 * 2 + koh + (wn >> 1) * 4) ^ l7) << 4) + kol * 8;
    const char* bB1 = (const char*)SH + 32768 + (wn & 1) * 8192 + l15 * 128
                      + (((1 * 2 + koh + (wn >> 1) * 4) ^ l7) << 4) + kol * 8;

#define LD_A(c, m, s) (*(const long long*)(((s) ? bA1 : bA0) + (c) * 16384 + (m) * 2048))
#define LD_B(c, n, s) (*(const long long*)(((s) ? bB1 : bB0) + (c) * 16384 + (n) * 2048))

#define BAR() __builtin_amdgcn_s_barrier()
#define VMC2() asm volatile("s_waitcnt vmcnt(2)" ::: "memory")
#define VMC0() asm volatile("s_waitcnt vmcnt(0)" ::: "memory")

    f32x4 acc[8][4];
    #pragma unroll
    for (int m = 0; m < 8; ++m)
        #pragma unroll
        for (int n = 0; n < 4; ++n)
            acc[m][n] = (f32x4){0.f, 0.f, 0.f, 0.f};

    long long bfr[4][2];
    long long fa0, fa1, fa2, fa3, fa4, fa5, fa6, fa7;

#define LDA_H(c, h) { fa0 = LD_A(c, 4*(h)+0, 0); fa1 = LD_A(c, 4*(h)+0, 1);       \
                      fa2 = LD_A(c, 4*(h)+1, 0); fa3 = LD_A(c, 4*(h)+1, 1);       \
                      fa4 = LD_A(c, 4*(h)+2, 0); fa5 = LD_A(c, 4*(h)+2, 1);       \
                      fa6 = LD_A(c, 4*(h)+3, 0); fa7 = LD_A(c, 4*(h)+3, 1); }
#define LDB_ALL(c) { _Pragma("unroll") for (int n = 0; n < 4; ++n) {              \
                       bfr[n][0] = LD_B(c, n, 0); bfr[n][1] = LD_B(c, n, 1); } }
#define MFMA_H(h) {                                                               \
    _Pragma("unroll") for (int n = 0; n < 4; ++n) {                               \
      acc[4*(h)+0][n] = __builtin_amdgcn_mfma_f32_16x16x32_fp8_fp8(bfr[n][0], fa0, acc[4*(h)+0][n], 0,0,0); \
      acc[4*(h)+0][n] = __builtin_amdgcn_mfma_f32_16x16x32_fp8_fp8(bfr[n][1], fa1, acc[4*(h)+0][n], 0,0,0); \
      acc[4*(h)+1][n] = __builtin_amdgcn_mfma_f32_16x16x32_fp8_fp8(bfr[n][0], fa2, acc[4*(h)+1][n], 0,0,0); \
      acc[4*(h)+1][n] = __builtin_amdgcn_mfma_f32_16x16x32_fp8_fp8(bfr[n][1], fa3, acc[4*(h)+1][n], 0,0,0); \
      acc[4*(h)+2][n] = __builtin_amdgcn_mfma_f32_16x16x32_fp8_fp8(bfr[n][0], fa4, acc[4*(h)+2][n], 0,0,0); \
      acc[4*(h)+2][n] = __builtin_amdgcn_mfma_f32_16x16x32_fp8_fp8(bfr[n][1], fa5, acc[4*(h)+2][n], 0,0,0); \
      acc[4*(h)+3][n] = __builtin_amdgcn_mfma_f32_16x16x32_fp8_fp8(bfr[n][0], fa6, acc[4*(h)+3][n], 0,0,0); \
      acc[4*(h)+3][n] = __builtin_amdgcn_mfma_f32_16x16x32_fp8_fp8(bfr[n][1], fa7, acc[4*(h)+3][n], 0,0,0); } }

    STAGE_B(gB, 0, 0, 0); STAGE_B(gB, 0, 1, 0);
    STAGE_A(gA, 0, 0, 0); STAGE_A(gA, 0, 1, 0);
    STAGE_B(gB, 1, 0, 1); STAGE_B(gB, 1, 1, 1);
    VMC2();
    BAR();

    const unsigned char* gAt = gA;
    const unsigned char* gBt = gB;
    for (int i = 0; i < 4; ++i) {
        const bool s23 = (i < 3);

        LDA_H(0, 0); LDB_ALL(0);
        STAGE_A(gAt, 1, 0, 1); STAGE_A(gAt, 1, 1, 1);
        BAR(); MFMA_H(0); BAR();

        LDA_H(0, 1);
        if (s23) { STAGE_B(gBt, 0, 0, 2); STAGE_B(gBt, 0, 1, 2); }
        BAR(); MFMA_H(1);
        if (s23) { VMC2(); } else { VMC0(); }
        BAR();

        LDA_H(1, 0); LDB_ALL(1);
        if (s23) { STAGE_A(gAt, 0, 0, 2); STAGE_A(gAt, 0, 1, 2); }
        BAR(); MFMA_H(0); BAR();

        LDA_H(1, 1);
        if (s23) { STAGE_B(gBt, 1, 0, 3); STAGE_B(gBt, 1, 1, 3); }
        BAR(); MFMA_H(1);
        if (s23) { VMC2(); }
        BAR();

        gAt += 128; gBt += 128;
    }

    {
        const int q  = lane >> 4;
        const int tr = wr * 128 + (lane & 15);
        #pragma unroll
        for (int n = 0; n < 4; ++n) {
            float4 bb = *(const float4*)(bias + n0 + wn * 64 + n * 16 + q * 4);
            const int g16 = wn * 4 + n;
            #pragma unroll
            for (int m = 0; m < 8; ++m) {
                const int trm = tr + m * 16;
                unsigned int pk = __builtin_amdgcn_cvt_pk_fp8_f32(
                    acc[m][n][0] + 16.f * bb.x, acc[m][n][1] + 16.f * bb.y, 0u, false);
                pk = __builtin_amdgcn_cvt_pk_fp8_f32(
                    acc[m][n][2] + 16.f * bb.z, acc[m][n][3] + 16.f * bb.w, pk, true);
                *(unsigned int*)(SH + trm * 256 + ((g16 ^ (trm & 15)) << 4) + q * 4) = pk;
            }
        }
        BAR();
        #pragma unroll
        for (int it = 0; it < 8; ++it) {
            const int f = it * 512 + tid;
            const int rr = f >> 4, gg = f & 15;
            uint4 v = *(const uint4*)(SH + rr * 256 + ((gg ^ (rr & 15)) << 4));
            *(uint4*)(C + (size_t)(row0 + rr) * 4096 + gg * 16 + n0) = v;
        }
    }
#undef STAGE_A
#undef STAGE_B
#undef LD_A
#undef LD_B
}

// ---------------- kernel 3: LDS-staged fp8-MFMA scores + softmax + pb-partials -------
__global__ __launch_bounds__(256) void mfscores(const unsigned char* __restrict__ Q,
                                                const unsigned char* __restrict__ K,
                                                float* __restrict__ P,
                                                float* __restrict__ pbpart)
{
    __shared__ __align__(16) unsigned char Qs[32768];
    __shared__ __align__(16) unsigned char Ks[32768];
    __shared__ float Pl[8 * 64];
    const int b = blockIdx.x, lc = blockIdx.y;       // (8, 64)
    const int tid = threadIdx.x, lane = tid & 63, w = tid >> 6;
    const int l0 = lc * 8;

    {
        const unsigned char* Qg = Q + (size_t)(b * 512 + l0) * 4096;
        const unsigned char* Kg = K + (size_t)(b * 512 + l0) * 4096;
        const int hhs = tid >> 5;
        const int dst = hhs * 512 + (((tid & 31) ^ hhs) << 4);
        #pragma unroll
        for (int i = 0; i < 8; ++i) {
            *(uint4*)(Qs + i * 4096 + dst) = *(const uint4*)(Qg + i * 4096 + tid * 16);
            *(uint4*)(Ks + i * 4096 + dst) = *(const uint4*)(Kg + i * 4096 + tid * 16);
        }
    }
    __syncthreads();

    const int colr = lane & 15;
    const int ko   = lane >> 4;
    const int lrow = w * 2 + (colr >> 3);
    const int hh   = colr & 7;
    const unsigned char* qb = Qs + lrow * 4096 + hh * 512 + (ko & 1) * 8;
    const unsigned char* kb = Ks + lrow * 4096 + hh * 512 + (ko & 1) * 8;
    const int koh = ko >> 1;

    f32x4 acc0 = (f32x4){0.f, 0.f, 0.f, 0.f};
    f32x4 acc1 = (f32x4){0.f, 0.f, 0.f, 0.f};
    #pragma unroll
    for (int kt = 0; kt < 8; ++kt) {
        const int s0 = (((2 * (2 * kt)     + koh) ^ hh) << 4);
        const int s1 = (((2 * (2 * kt + 1) + koh) ^ hh) << 4);
        long long a0 = *(const long long*)(qb + s0);
        long long b0 = *(const long long*)(kb + s0);
        long long a1 = *(const long long*)(qb + s1);
        long long b1 = *(const long long*)(kb + s1);
        acc0 = __builtin_amdgcn_mfma_f32_16x16x32_fp8_fp8(a0, b0, acc0, 0, 0, 0);
        acc1 = __builtin_amdgcn_mfma_f32_16x16x32_fp8_fp8(a1, b1, acc1, 0, 0, 0);
    }

    const int lpr = ko >> 1;
    const int lpc = (lane >> 3) & 1;
    #pragma unroll
    for (int r = 0; r < 4; ++r) {
        float s = (acc0[r] + acc1[r]) * 1.7263349150062e-4f;   // 1/(256*sqrt(512))
        float m = s;
        m = fmaxf(m, __shfl_xor(m, 1));
        m = fmaxf(m, __shfl_xor(m, 2));
        m = fmaxf(m, __shfl_xor(m, 4));
        float e = __expf(s - m);
        float ss = e;
        ss += __shfl_xor(ss, 1);
        ss += __shfl_xor(ss, 2);
        ss += __shfl_xor(ss, 4);
        float p = e / ss + 63.875f;               // fold uniform part
        if (lpr == lpc)
            Pl[(w * 2 + lpr) * 64 + ((ko & 1) * 4 + r) * 8 + (lane & 7)] = p;
    }
    __syncthreads();

    {
        const int l = tid >> 5, off = (tid & 31) * 2;
        float2 v = *(const float2*)&Pl[l * 64 + off];
        *(float2*)(P + (size_t)(b * 512 + l0 + l) * 64 + off) = v;
    }
    if (tid < 64) {
        float s = 0.f;
        #pragma unroll
        for (int l = 0; l < 8; ++l) s += Pl[l * 64 + tid];
        pbpart[((size_t)b * 64 + lc) * 64 + tid] = s;
    }
}

// ---------------- kernel 4: ypart[lc,b,hg,d] = sum_{l in 128-chunk} P' * Xv ----------
__global__ __launch_bounds__(256) void ykern(const float* __restrict__ P,
                                             const float* __restrict__ Xv,
                                             float* __restrict__ ypart)
{
    __shared__ float Pl[128 * 64];
    __shared__ float Xl[128 * 64];
    const int b = blockIdx.x, dt = blockIdx.y, lc = blockIdx.z;   // (8, 8, 4)
    const int tid = threadIdx.x;
    const int tm = tid & 15, te = tid >> 4;

    const float* Pg = P + ((size_t)b * 512 + lc * 128) * 64;
    #pragma unroll
    for (int i = 0; i < 8; ++i)
        *(float4*)&Pl[(i * 256 + tid) * 4] = *(const float4*)(Pg + (size_t)(i * 256 + tid) * 4);
    const float* Xg = Xv + ((size_t)b * 512 + lc * 128) * 512 + dt * 64;
    #pragma unroll
    for (int i = 0; i < 8; ++i) {
        int flat = i * 256 + tid;
        int r = flat >> 4, q = flat & 15;
        *(float4*)&Xl[r * 64 + q * 4] = *(const float4*)(Xg + (size_t)r * 512 + q * 4);
    }
    __syncthreads();

    float4 acc[4];
    #pragma unroll
    for (int i = 0; i < 4; ++i) acc[i] = make_float4(0.f, 0.f, 0.f, 0.f);

    for (int l = 0; l < 128; ++l) {
        float4 pv = *(const float4*)&Pl[l * 64 + tm * 4];
        float4 xv = *(const float4*)&Xl[l * 64 + te * 4];
        acc[0].x += pv.x * xv.x; acc[0].y += pv.x * xv.y; acc[0].z += pv.x * xv.z; acc[0].w += pv.x * xv.w;
        acc[1].x += pv.y * xv.x; acc[1].y += pv.y * xv.y; acc[1].z += pv.y * xv.z; acc[1].w += pv.y * xv.w;
        acc[2].x += pv.z * xv.x; acc[2].y += pv.z * xv.y; acc[2].z += pv.z * xv.z; acc[2].w += pv.z * xv.w;
        acc[3].x += pv.w * xv.x; acc[3].y += pv.w * xv.y; acc[3].z += pv.w * xv.z; acc[3].w += pv.w * xv.w;
    }
    #pragma unroll
    for (int i = 0; i < 4; ++i)
        *(float4*)&ypart[(((size_t)lc * 8 + b) * 64 + tm * 4 + i) * 512 + dt * 64 + te * 4] = acc[i];
}

// ---------------- kernel 5: split-K vgemm (sums 4 ypart slices in A-stage) -----------
__global__ __launch_bounds__(256) void vgemm(const float* __restrict__ ypart,
                                             const float* __restrict__ Wv,
                                             float* __restrict__ partial)
{
    __shared__ float Al[64 * 64];
    __shared__ float Bl[64 * 64];
    const int et = blockIdx.x, kc = blockIdx.y;
    const int g = kc >> 3, d0 = (kc & 7) * 64, e0 = et * 64;
    const int tid = threadIdx.x;
    const int tm = tid & 15, te = tid >> 4;

    #pragma unroll
    for (int i = 0; i < 4; ++i) {
        int flat = i * 256 + tid;
        int bh = flat >> 4, dq = flat & 15;
        int yrow = (bh >> 3) * 64 + (bh & 7) * 8 + g;
        size_t base = ((size_t)(yrow >> 6) * 64 + (yrow & 63)) * 512 + d0 + dq * 4;
        float4 v = *(const float4*)(ypart + base);
        #pragma unroll
        for (int lc = 1; lc < 4; ++lc) {
            float4 t = *(const float4*)(ypart + (size_t)lc * 262144 + base);
            v.x += t.x; v.y += t.y; v.z += t.z; v.w += t.w;
        }
        *(float4*)&Al[bh * 64 + ((dq ^ (bh >> 2)) << 2)] = v;
    }
    #pragma unroll
    for (int i = 0; i < 4; ++i) {
        int flat = i * 256 + tid;
        int kk = flat >> 4, eq = flat & 15;
        *(float4*)&Bl[kk * 64 + eq * 4] =
            *(const float4*)(Wv + (size_t)(d0 + kk) * 4096 + g * 512 + e0 + eq * 4);
    }
    __syncthreads();

    float4 acc[4];
    #pragma unroll
    for (int j = 0; j < 4; ++j) acc[j] = make_float4(0.f, 0.f, 0.f, 0.f);

    for (int k = 0; k < 64; ++k) {
        float4 b4 = *(const float4*)&Bl[k * 64 + te * 4];
        const int gcol = (((k >> 2) ^ tm) << 2) + (k & 3);
        #pragma unroll
        for (int j = 0; j < 4; ++j) {
            float a = Al[(tm * 4 + j) * 64 + gcol];
            acc[j].x += a * b4.x; acc[j].y += a * b4.y;
            acc[j].z += a * b4.z; acc[j].w += a * b4.w;
        }
    }
    #pragma unroll
    for (int j = 0; j < 4; ++j)
        *(float4*)&partial[(size_t)kc * 32768 + (tm * 4 + j) * 512 + e0 + te * 4] = acc[j];
}

// ---------------- kernel 6: finalize: out = sum_kc partial + sum_g c*bv --------------
__global__ __launch_bounds__(256) void finalize(const float* __restrict__ partial,
                                                const float* __restrict__ pbpart,
                                                const float* __restrict__ bv,
                                                float* __restrict__ out)
{
    __shared__ float red[64];
    __shared__ float csh[8];
    const int blk = blockIdx.x;          // 128 blocks: (b,h) x half-e
    const int tid = threadIdx.x;
    const int b = blk >> 4, h = (blk >> 1) & 7;
    const int e = (blk & 1) * 256 + tid;

    if (tid < 64) {
        const int g = tid >> 3, seg = tid & 7;
        float s = 0.f;
        #pragma unroll
        for (int j = 0; j < 8; ++j)
            s += pbpart[((size_t)b * 64 + seg * 8 + j) * 64 + h * 8 + g];
        red[tid] = s;
    }
    __syncthreads();
    if (tid < 8) {
        float s = 0.f;
        #pragma unroll
        for (int seg = 0; seg < 8; ++seg) s += red[tid + seg * 8];
        csh[tid] = s;
    }
    __syncthreads();

    const int i = ((b * 8 + h) << 9) + e;
    float s = 0.f;
    #pragma unroll
    for (int kc = 0; kc < 64; ++kc) s += partial[(size_t)kc * 32768 + i];
    float bt = 0.f;
    #pragma unroll
    for (int g = 0; g < 8; ++g) bt += csh[g] * bv[g * 512 + e];
    out[i] = s + bt;
}

extern "C" void kernel_launch(void* const* d_in, const int* in_sizes, int n_in,
                              void* d_out, int out_size, void* d_ws, size_t ws_size,
                              hipStream_t stream)
{
    const float* queries = (const float*)d_in[0];
    const float* keys    = (const float*)d_in[1];
    const float* values  = (const float*)d_in[2];
    const float* Wq      = (const float*)d_in[3];
    const float* bq      = (const float*)d_in[4];
    const float* Wk      = (const float*)d_in[5];
    const float* bk      = (const float*)d_in[6];
    const float* Wv      = (const float*)d_in[7];
    const float* bv      = (const float*)d_in[8];

    unsigned char* xq  = (unsigned char*)d_ws;          // 2 MB each
    unsigned char* xk  = xq  + (1u << 21);
    unsigned char* wtq = xk  + (1u << 21);
    unsigned char* wtk = wtq + (1u << 21);
    unsigned char* Q   = wtk + (1u << 21);              // 16 MB each
    unsigned char* Kb  = Q   + (1u << 24);
    float* P      = (float*)(Kb + (1u << 24));
    float* pbpart = P + 262144;
    float* ypart  = pbpart + 32768;                     // 4 x 262144 floats
    float* part   = ypart + 4 * 262144;

    prep<<<dim3(2048, 1, 4), 256, 0, stream>>>(queries, keys, xq, xk, Wq, Wk, wtq, wtk);
    gemm_bt256<<<dim3(16, 16, 2), 512, 0, stream>>>(xq, xk, wtq, wtk, bq, bk, Q, Kb);
    mfscores<<<dim3(8, 64), 256, 0, stream>>>(Q, Kb, P, pbpart);
    ykern<<<dim3(8, 8, 4), 256, 0, stream>>>(P, values, ypart);
    vgemm<<<dim3(8, 64), 256, 0, stream>>>(ypart, Wv, part);
    finalize<<<dim3(128), 256, 0, stream>>>(part, pbpart, bv, (float*)d_out);
}